// Round 10
// baseline (667.174 us; speedup 1.0000x reference)
//
#include <hip/hip_runtime.h>
#include <hip/hip_bf16.h>

#define NB 16
#define TQ 128
#define TT 128
#define DT 128
#define NH 8
#define DQK 64
#define DV 64

typedef _Float16 f16;
typedef _Float16 f16x4 __attribute__((ext_vector_type(4)));
typedef float f32x4 __attribute__((ext_vector_type(4)));

// ---------------------------------------------------------------------------
// Projection: OUT[b][h][row][dqk] = sum_k X[b*128+row][k] * W[k][h*64+dqk]
// X: (2048,128) row-major, W: (128,512) row-major. Tile 64x64, K=128 staged.
// ---------------------------------------------------------------------------
__global__ __launch_bounds__(256) void proj_kernel(const float* __restrict__ X,
                                                   const float* __restrict__ W,
                                                   float* __restrict__ out) {
  __shared__ float Xs[64][132];
  __shared__ float Ws[128][68];
  const int tid = threadIdx.x;
  const int m0 = blockIdx.x * 64;
  const int n0 = blockIdx.y * 64;
#pragma unroll
  for (int i = 0; i < 8; ++i) {
    int idx = i * 256 + tid;
    int r = idx >> 5;
    int c = (idx & 31) << 2;
    *(float4*)&Xs[r][c] = *(const float4*)&X[(m0 + r) * DT + c];
  }
#pragma unroll
  for (int i = 0; i < 8; ++i) {
    int idx = i * 256 + tid;
    int r = idx >> 4;
    int c = (idx & 15) << 2;
    *(float4*)&Ws[r][c] = *(const float4*)&W[r * (NH * DQK) + n0 + c];
  }
  __syncthreads();
  const int tm = (tid >> 4) << 2;
  const int tn = (tid & 15) << 2;
  float acc[4][4] = {};
#pragma unroll 8
  for (int k = 0; k < 128; ++k) {
    float a0 = Xs[tm + 0][k];
    float a1 = Xs[tm + 1][k];
    float a2 = Xs[tm + 2][k];
    float a3 = Xs[tm + 3][k];
    float4 bv = *(const float4*)&Ws[k][tn];
    acc[0][0] += a0 * bv.x; acc[0][1] += a0 * bv.y; acc[0][2] += a0 * bv.z; acc[0][3] += a0 * bv.w;
    acc[1][0] += a1 * bv.x; acc[1][1] += a1 * bv.y; acc[1][2] += a1 * bv.z; acc[1][3] += a1 * bv.w;
    acc[2][0] += a2 * bv.x; acc[2][1] += a2 * bv.y; acc[2][2] += a2 * bv.z; acc[2][3] += a2 * bv.w;
    acc[3][0] += a3 * bv.x; acc[3][1] += a3 * bv.y; acc[3][2] += a3 * bv.z; acc[3][3] += a3 * bv.w;
  }
#pragma unroll
  for (int i = 0; i < 4; ++i) {
    int R = m0 + tm + i;
    int C = n0 + tn;
    int o = (R >> 7) * (NH * TQ * DQK) + (C >> 6) * (TQ * DQK) + (R & 127) * DQK + (C & 63);
    float4 ov = make_float4(acc[i][0], acc[i][1], acc[i][2], acc[i][3]);
    *(float4*)&out[o] = ov;
  }
}

// ---------------------------------------------------------------------------
// Fused scores -> masked softmax -> attn write (512 MiB) -> PV accumulate.
// Grid (4 qtiles, 8 heads, 16 batch), 256 threads = 4 waves.
// Each wave privately owns 8 q-rows: NO barriers after staging, so streaming
// attn stores never cross a __syncthreads vmcnt-drain. Mask bit-packed in
// registers; V and e held as f16 in LDS so the store loop issues no VMEM loads.
// attn stores are nontemporal (write-once stream, never re-read) via native
// ext_vector f32x4 (HIP float4 is a class type the builtin rejects).
// ---------------------------------------------------------------------------
__global__ __launch_bounds__(256) void attn_kernel(
    const float* __restrict__ qh, const float* __restrict__ kh,
    const float* __restrict__ v, const float* __restrict__ mask,
    float* __restrict__ attn_out, float* __restrict__ outh) {
  __shared__ float khs[128][68];   // 34816 B
  __shared__ float qhs[32][68];    //  8704 B
  __shared__ f16   vsh[128][68];   // 17408 B
  __shared__ f16   esw[4][8][136]; //  8704 B   (e[t] at idx t + 2*(t>>5))

  const int tid = threadIdx.x;
  const int q0 = blockIdx.x * 32;
  const int h = blockIdx.y;
  const int b = blockIdx.z;
  const int bh = b * NH + h;

  // ---- stage K tile (128x64 f32) ----
#pragma unroll
  for (int i = 0; i < 8; ++i) {
    int idx = i * 256 + tid;
    int t = idx >> 4;
    int c = (idx & 15) << 2;
    *(float4*)&khs[t][c] = *(const float4*)&kh[(bh * TT + t) * DQK + c];
  }
  // ---- stage Q tile (32x64 f32) ----
#pragma unroll
  for (int i = 0; i < 2; ++i) {
    int idx = i * 256 + tid;
    int r = idx >> 4;
    int c = (idx & 15) << 2;
    *(float4*)&qhs[r][c] = *(const float4*)&qh[(bh * TQ + q0 + r) * DQK + c];
  }
  // ---- stage V tile (128x64) as f16 ----
#pragma unroll
  for (int i = 0; i < 8; ++i) {
    int idx = i * 256 + tid;
    int t = idx >> 4;
    int c = (idx & 15) << 2;
    float4 val = *(const float4*)&v[(b * TT + t) * DV + c];
    f16x4 pv;
    pv.x = (f16)val.x; pv.y = (f16)val.y; pv.z = (f16)val.z; pv.w = (f16)val.w;
    *(f16x4*)&vsh[t][c] = pv;
  }

  // lane mapping for the d-phase: lane = tg*16 + dd; covers t in [tg*32,tg*32+32), d in [dd*4, dd*4+4)
  const int lane = tid & 63;
  const int w = tid >> 6;
  const int tg = lane >> 4;
  const int dd = lane & 15;
  const int d0 = dd << 2;

  // ---- pack observation mask into 4 bit-registers (bit i = t = tg*32+i) ----
  unsigned mb0 = 0u, mb1 = 0u, mb2 = 0u, mb3 = 0u;
#pragma unroll
  for (int i = 0; i < 32; ++i) {
    int t = tg * 32 + i;
    float4 mv = *(const float4*)&mask[(b * TT + t) * DV + d0];
    mb0 |= (mv.x > 0.5f ? 1u : 0u) << i;
    mb1 |= (mv.y > 0.5f ? 1u : 0u) << i;
    mb2 |= (mv.z > 0.5f ? 1u : 0u) << i;
    mb3 |= (mv.w > 0.5f ? 1u : 0u) << i;
  }
  __syncthreads();  // the ONLY barrier

  // ---- scores + exp (wave-private; lane l handles t=l and t=l+64) ----
#pragma unroll
  for (int j = 0; j < 8; ++j) {
    const int qq = w * 8 + j;
    float s0 = 0.f, s1 = 0.f;
#pragma unroll
    for (int c = 0; c < 64; c += 4) {
      float4 qv = *(const float4*)&qhs[qq][c];
      float4 ka = *(const float4*)&khs[lane][c];
      float4 kb = *(const float4*)&khs[lane + 64][c];
      s0 += qv.x * ka.x + qv.y * ka.y + qv.z * ka.z + qv.w * ka.w;
      s1 += qv.x * kb.x + qv.y * kb.y + qv.z * kb.z + qv.w * kb.w;
    }
    s0 *= 0.125f;  // 1/sqrt(64)
    s1 *= 0.125f;
    float m = fmaxf(s0, s1);
#pragma unroll
    for (int off = 32; off > 0; off >>= 1) m = fmaxf(m, __shfl_xor(m, off));
    esw[w][j][lane + 2 * (lane >> 5)] = (f16)__expf(s0 - m);
    esw[w][j][lane + 68 + 2 * (lane >> 5)] = (f16)__expf(s1 - m);
  }

  // ---- Z_d = sum_t mask[t,d]*e[t]  (partial over this lane's 32 t) ----
  float4 Zr[8];
#pragma unroll
  for (int j = 0; j < 8; ++j) Zr[j] = make_float4(0.f, 0.f, 0.f, 0.f);
  const int ebase = tg * 34;
#pragma unroll 4
  for (int i = 0; i < 32; ++i) {
    float fx = ((mb0 >> i) & 1) ? 1.f : 0.f;
    float fy = ((mb1 >> i) & 1) ? 1.f : 0.f;
    float fz = ((mb2 >> i) & 1) ? 1.f : 0.f;
    float fw = ((mb3 >> i) & 1) ? 1.f : 0.f;
#pragma unroll
    for (int j = 0; j < 8; ++j) {
      float e = (float)esw[w][j][ebase + i];
      Zr[j].x += fx * e;
      Zr[j].y += fy * e;
      Zr[j].z += fz * e;
      Zr[j].w += fw * e;
    }
  }
  // cross-t-group reduce (intra-wave) then reciprocal
#pragma unroll
  for (int j = 0; j < 8; ++j) {
    float4 z = Zr[j];
    z.x += __shfl_xor(z.x, 16); z.x += __shfl_xor(z.x, 32);
    z.y += __shfl_xor(z.y, 16); z.y += __shfl_xor(z.y, 32);
    z.z += __shfl_xor(z.z, 16); z.z += __shfl_xor(z.z, 32);
    z.w += __shfl_xor(z.w, 16); z.w += __shfl_xor(z.w, 32);
    Zr[j].x = 1.f / z.x;
    Zr[j].y = 1.f / z.y;
    Zr[j].z = 1.f / z.z;
    Zr[j].w = 1.f / z.w;
  }

  // ---- attn write (nontemporal) + PV accumulate ----
  float4 acc[8];
#pragma unroll
  for (int j = 0; j < 8; ++j) acc[j] = make_float4(0.f, 0.f, 0.f, 0.f);
  float* abase = attn_out + ((size_t)(bh * TQ + q0 + w * 8)) * (TT * DV) + tg * 32 * DV + d0;
#pragma unroll 2
  for (int i = 0; i < 32; ++i) {
    int t = tg * 32 + i;
    f16x4 vv = *(const f16x4*)&vsh[t][d0];
    float vx = (float)vv.x, vy = (float)vv.y, vz = (float)vv.z, vw = (float)vv.w;
    float fx = ((mb0 >> i) & 1) ? 1.f : 0.f;
    float fy = ((mb1 >> i) & 1) ? 1.f : 0.f;
    float fz = ((mb2 >> i) & 1) ? 1.f : 0.f;
    float fw = ((mb3 >> i) & 1) ? 1.f : 0.f;
#pragma unroll
    for (int j = 0; j < 8; ++j) {
      float e = (float)esw[w][j][ebase + i];
      f32x4 a;
      a.x = fx * (e * Zr[j].x);
      a.y = fy * (e * Zr[j].y);
      a.z = fz * (e * Zr[j].z);
      a.w = fw * (e * Zr[j].w);
      __builtin_nontemporal_store(a, (f32x4*)(abase + (size_t)j * (TT * DV) + i * DV));
      acc[j].x += a.x * vx;
      acc[j].y += a.y * vy;
      acc[j].z += a.z * vz;
      acc[j].w += a.w * vw;
    }
  }

  // ---- reduce PV across t-groups (intra-wave) and write per-head output ----
#pragma unroll
  for (int j = 0; j < 8; ++j) {
    float4 a = acc[j];
    a.x += __shfl_xor(a.x, 16); a.x += __shfl_xor(a.x, 32);
    a.y += __shfl_xor(a.y, 16); a.y += __shfl_xor(a.y, 32);
    a.z += __shfl_xor(a.z, 16); a.z += __shfl_xor(a.z, 32);
    a.w += __shfl_xor(a.w, 16); a.w += __shfl_xor(a.w, 32);
    if (tg == 0) {
      int q = q0 + w * 8 + j;
      *(float4*)&outh[(bh * TQ + q) * DV + d0] = a;
    }
  }
}

// ---------------------------------------------------------------------------
// out0[r][c] = sum_k outh_view[r][k] * Wo[k][c];  r=b*128+q, k=h*64+dv, N=128.
// Block: 8 rows x 128 cols, 256 threads. 256 blocks.
// ---------------------------------------------------------------------------
__global__ __launch_bounds__(256) void out_proj_kernel(const float* __restrict__ outh,
                                                       const float* __restrict__ Wo,
                                                       float* __restrict__ out0) {
  __shared__ float As[8][516];
  const int tid = threadIdx.x;
  const int r0 = blockIdx.x * 8;
#pragma unroll
  for (int i = 0; i < 4; ++i) {
    int idx = i * 256 + tid;
    int r = idx >> 7;
    int c = (idx & 127) << 2;
    int R = r0 + r;
    int src = (R >> 7) * (NH * TQ * DV) + (c >> 6) * (TQ * DV) + (R & 127) * DV + (c & 63);
    *(float4*)&As[r][c] = *(const float4*)&outh[src];
  }
  __syncthreads();
  const int cc = tid & 127;
  const int rr = (tid >> 7) << 2;
  float acc[4] = {0.f, 0.f, 0.f, 0.f};
#pragma unroll 4
  for (int k = 0; k < 512; k += 4) {
    float w0 = Wo[(k + 0) * 128 + cc];
    float w1 = Wo[(k + 1) * 128 + cc];
    float w2 = Wo[(k + 2) * 128 + cc];
    float w3 = Wo[(k + 3) * 128 + cc];
#pragma unroll
    for (int j = 0; j < 4; ++j) {
      float4 a4 = *(const float4*)&As[rr + j][k];
      acc[j] += a4.x * w0 + a4.y * w1 + a4.z * w2 + a4.w * w3;
    }
  }
#pragma unroll
  for (int j = 0; j < 4; ++j) {
    out0[(r0 + rr + j) * 128 + cc] = acc[j];
  }
}

extern "C" void kernel_launch(void* const* d_in, const int* in_sizes, int n_in,
                              void* d_out, int out_size, void* d_ws, size_t ws_size,
                              hipStream_t stream) {
  (void)in_sizes; (void)n_in; (void)out_size; (void)ws_size;
  const float* q    = (const float*)d_in[0];
  const float* k    = (const float*)d_in[1];
  const float* v    = (const float*)d_in[2];
  const float* mask = (const float*)d_in[3];
  const float* Wq   = (const float*)d_in[4];
  const float* Wk   = (const float*)d_in[5];
  const float* Wo   = (const float*)d_in[6];

  float* out0     = (float*)d_out;
  float* attn_out = out0 + (size_t)NB * TQ * 128;          // 262144 floats in

  float* qh_ws = (float*)d_ws;                              // 4 MiB
  float* kh_ws = qh_ws + (size_t)NB * NH * TQ * DQK;        // 4 MiB
  float* outh  = kh_ws + (size_t)NB * NH * TT * DQK;        // 4 MiB

  dim3 pg(32, 8);
  proj_kernel<<<pg, 256, 0, stream>>>(q, Wq, qh_ws);
  proj_kernel<<<pg, 256, 0, stream>>>(k, Wk, kh_ws);
  attn_kernel<<<dim3(4, 8, 16), 256, 0, stream>>>(qh_ws, kh_ws, v, mask, attn_out, outh);
  out_proj_kernel<<<256, 256, 0, stream>>>(outh, Wo, out0);
}